// Round 7
// baseline (171.300 us; speedup 1.0000x reference)
//
#include <hip/hip_runtime.h>

#define N_TOK 2048
#define DMODEL 1024
#define NH 16
#define NKV 4
#define HDIM 64
#define SCALE_LOG2E 0.1803368801111204f  // (1/8) * log2(e)

typedef __attribute__((ext_vector_type(8))) short short8;
typedef __attribute__((ext_vector_type(4))) float f32x4;
typedef unsigned short u16;
typedef unsigned int u32;

__device__ __forceinline__ u16 f2bf(float x) {
    u32 u = __float_as_uint(x);
    u += 0x7FFF + ((u >> 16) & 1);   // round-to-nearest-even
    return (u16)(u >> 16);
}
__device__ __forceinline__ u32 pack2(float a, float b) {
    return (u32)f2bf(a) | ((u32)f2bf(b) << 16);
}
// pack high halves (truncating bf16) of two floats into one u32: [bf(a) | bf(b)<<16]
__device__ __forceinline__ u32 pack2t(float a, float b) {
    return __builtin_amdgcn_perm(__float_as_uint(b), __float_as_uint(a), 0x07060302u);
}

// ---------------------------------------------------------------------------
// prep: z=0..3 transpose W (K x NC) -> Wt (NC x K) bf16; z=4 convert x -> bf16
// ---------------------------------------------------------------------------
__global__ __launch_bounds__(256) void prep(
    const float* __restrict__ Wq, const float* __restrict__ Wk,
    const float* __restrict__ Wv, const float* __restrict__ Wo,
    const float* __restrict__ x,
    u16* __restrict__ Wqt, u16* __restrict__ Wkt, u16* __restrict__ Wvt,
    u16* __restrict__ Wot, u16* __restrict__ xb)
{
    const int z = blockIdx.z;
    const int t = threadIdx.x;
    if (z == 4) {
        size_t base = ((size_t)(blockIdx.y * 16 + blockIdx.x)) * 8192;
#pragma unroll
        for (int i = 0; i < 8; ++i) {
            float4 v = *(const float4*)(x + base + i * 1024 + t * 4);
            uint2 p; p.x = pack2(v.x, v.y); p.y = pack2(v.z, v.w);
            *(uint2*)(xb + base + i * 1024 + t * 4) = p;
        }
        return;
    }
    const float* W; u16* Wt; int NC;
    if      (z == 0) { W = Wq; Wt = Wqt; NC = 1024; }
    else if (z == 1) { W = Wk; Wt = Wkt; NC = 256; }
    else if (z == 2) { W = Wv; Wt = Wvt; NC = 256; }
    else             { W = Wo; Wt = Wot; NC = 1024; }
    const int n0 = blockIdx.x * 64;
    if (n0 >= NC) return;
    const int k0 = blockIdx.y * 64;
    __shared__ float T[64][68];
    const int row = t >> 2, cs = (t & 3) * 16;
#pragma unroll
    for (int i = 0; i < 4; ++i)
        *(float4*)&T[row][cs + i * 4] =
            *(const float4*)(W + (size_t)(k0 + row) * NC + n0 + cs + i * 4);
    __syncthreads();
    const int nl = t >> 2, ks = (t & 3) * 16;
    u32 pk[8];
#pragma unroll
    for (int i = 0; i < 8; ++i)
        pk[i] = pack2(T[ks + 2 * i][nl], T[ks + 2 * i + 1][nl]);
    u16* dst = Wt + (size_t)(n0 + nl) * DMODEL + k0 + ks;
    uint4 w0; w0.x = pk[0]; w0.y = pk[1]; w0.z = pk[2]; w0.w = pk[3];
    uint4 w1; w1.x = pk[4]; w1.y = pk[5]; w1.z = pk[6]; w1.w = pk[7];
    *(uint4*)(dst) = w0;
    *(uint4*)(dst + 8) = w1;
}

// ---------------------------------------------------------------------------
// QKV GEMM: tile 128x128, BK=32, 4 waves of 64x64.
// grid (16,12): by<8 -> Q (rope, x SCALE_LOG2E); 8,9 -> K (rope);
// 10,11 -> V in fragment-packed layout FV:
//   FV[((((g*32+kt)*4+dt)*2+c)*64 + quad*16 + l15)*8 + j]
//     = V[token = kt*64 + c*32 + quad*8 + j][d = dt*16 + l15]  (per kv-head g)
// ---------------------------------------------------------------------------
__global__ __launch_bounds__(256, 2) void gemm_qkv(
    const u16* __restrict__ A,
    const u16* __restrict__ B0, const u16* __restrict__ B1, const u16* __restrict__ B2,
    u16* __restrict__ D0, u16* __restrict__ D1, u16* __restrict__ FVout,
    const float* __restrict__ fc, const float* __restrict__ fs)
{
    __shared__ u16 As[128][40];
    __shared__ u16 Bs[128][40];
    const int t = threadIdx.x;
    const int m0 = blockIdx.x * 128;
    const int by = blockIdx.y;

    const u16* Bt; int nl0, ep;           // ep: 1 rope bf16, 2 FV
    u16* dbf = nullptr; int dstride = 0; float epsc = 1.f;
    if (by < 8)       { Bt = B0; nl0 = by * 128;        dbf = D0; ep = 1; dstride = 1024;
                        epsc = SCALE_LOG2E; }
    else if (by < 10) { Bt = B1; nl0 = (by - 8) * 128;  dbf = D1; ep = 1; dstride = 256; }
    else              { Bt = B2; nl0 = (by - 10) * 128; ep = 2; }

    const int w = t >> 6, lane = t & 63;
    const int quad = lane >> 4, l15 = lane & 15;
    const int wm = (w >> 1) * 64, wn = (w & 1) * 64;
    const int srow = t >> 1, sk = (t & 1) * 16;

    const u16* Ap = A + (size_t)(m0 + srow) * DMODEL + sk;
    const u16* Bp = Bt + (size_t)(nl0 + srow) * DMODEL + sk;

    f32x4 acc[4][4];
#pragma unroll
    for (int i = 0; i < 4; ++i)
#pragma unroll
        for (int j = 0; j < 4; ++j) acc[i][j] = {0.f, 0.f, 0.f, 0.f};

    uint4 ar0 = *(const uint4*)(Ap);
    uint4 ar1 = *(const uint4*)(Ap + 8);
    uint4 br0 = *(const uint4*)(Bp);
    uint4 br1 = *(const uint4*)(Bp + 8);

    for (int k0 = 0; k0 < DMODEL; k0 += 32) {
        __syncthreads();
        *(uint4*)&As[srow][sk]     = ar0;
        *(uint4*)&As[srow][sk + 8] = ar1;
        *(uint4*)&Bs[srow][sk]     = br0;
        *(uint4*)&Bs[srow][sk + 8] = br1;
        __syncthreads();
        if (k0 + 32 < DMODEL) {
            ar0 = *(const uint4*)(Ap + k0 + 32);
            ar1 = *(const uint4*)(Ap + k0 + 40);
            br0 = *(const uint4*)(Bp + k0 + 32);
            br1 = *(const uint4*)(Bp + k0 + 40);
        }
        short8 af[4], bf[4];
#pragma unroll
        for (int i = 0; i < 4; ++i)
            af[i] = *(const short8*)&As[wm + i * 16 + l15][quad * 8];
#pragma unroll
        for (int j = 0; j < 4; ++j)
            bf[j] = *(const short8*)&Bs[wn + j * 16 + l15][quad * 8];
#pragma unroll
        for (int i = 0; i < 4; ++i)
#pragma unroll
            for (int j = 0; j < 4; ++j)
                acc[i][j] = __builtin_amdgcn_mfma_f32_16x16x32_bf16(af[i], bf[j], acc[i][j], 0, 0, 0);
    }

#pragma unroll
    for (int i = 0; i < 4; ++i)
#pragma unroll
        for (int j = 0; j < 4; ++j) {
            const int cl = nl0 + wn + j * 16 + l15;
#pragma unroll
            for (int r4 = 0; r4 < 4; ++r4) {
                const int r = m0 + wm + i * 16 + quad * 4 + r4;
                float own = acc[i][j][r4];
                if (ep == 1) {
                    float other = __shfl_xor(own, 1, 64);
                    const int p = (cl & 63) >> 1;
                    const float c = fc[r * 32 + p] * epsc, s = fs[r * 32 + p] * epsc;
                    float outv = ((cl & 1) == 0) ? (own * c - other * s)
                                                 : (other * s + own * c);
                    dbf[(size_t)r * dstride + cl] = f2bf(outv);
                } else {
                    const int g = cl >> 6, d = cl & 63;
                    const int dt = d >> 4, l15v = d & 15;
                    const int kt = r >> 6, klo = r & 63;
                    const int c = klo >> 5, k5 = klo & 31;
                    const int qd = k5 >> 3, jv = k5 & 7;
                    size_t idx = ((((size_t)(g * 32 + kt) * 4 + dt) * 2 + c) * 64
                                  + qd * 16 + l15v) * 8 + jv;
                    FVout[idx] = f2bf(own);
                }
            }
        }
}

// ---------------------------------------------------------------------------
// Output GEMM with fused attention-partial combine:
//   A[tok][k] = (Oa[tok][k] + Ob[tok][k]) / (La[h][tok] + Lb[h][tok]), h=k>>6
// tile 64x128, BK=32, 4 waves of 32x64, fp32 out. grid (32,8).
// ---------------------------------------------------------------------------
__global__ __launch_bounds__(256, 2) void gemm_out(
    const float* __restrict__ Oa, const float* __restrict__ Ob,
    const float* __restrict__ La, const float* __restrict__ Lb,
    const u16* __restrict__ Bt, float* __restrict__ Dout)
{
    __shared__ u16 As[64][40];
    __shared__ u16 Bs[128][40];
    const int t = threadIdx.x;
    const int m0 = blockIdx.x * 64;
    const int nl0 = blockIdx.y * 128;

    const int w = t >> 6, lane = t & 63;
    const int quad = lane >> 4, l15 = lane & 15;
    const int wm = (w >> 1) * 32, wn = (w & 1) * 64;
    const int arow = t >> 2, acol = (t & 3) * 8;
    const int brow = t >> 1, bcol = (t & 1) * 16;

    const u16* Bp = Bt + (size_t)(nl0 + brow) * DMODEL + bcol;

    f32x4 acc[2][4];
#pragma unroll
    for (int i = 0; i < 2; ++i)
#pragma unroll
        for (int j = 0; j < 4; ++j) acc[i][j] = {0.f, 0.f, 0.f, 0.f};

    // staged-A producer: loads Oa/Ob/l, normalizes, packs bf16x8 into uint4
    auto load_a = [&](int k0) -> uint4 {
        const size_t base = (size_t)(m0 + arow) * DMODEL + k0 + acol;
        float4 a0 = *(const float4*)(Oa + base);
        float4 a1 = *(const float4*)(Oa + base + 4);
        float4 b0 = *(const float4*)(Ob + base);
        float4 b1 = *(const float4*)(Ob + base + 4);
        const int h = (k0 + acol) >> 6;
        const float inv = 1.f / (La[(size_t)h * N_TOK + m0 + arow]
                               + Lb[(size_t)h * N_TOK + m0 + arow]);
        uint4 r;
        r.x = pack2((a0.x + b0.x) * inv, (a0.y + b0.y) * inv);
        r.y = pack2((a0.z + b0.z) * inv, (a0.w + b0.w) * inv);
        r.z = pack2((a1.x + b1.x) * inv, (a1.y + b1.y) * inv);
        r.w = pack2((a1.z + b1.z) * inv, (a1.w + b1.w) * inv);
        return r;
    };

    uint4 ar  = load_a(0);
    uint4 br0 = *(const uint4*)(Bp);
    uint4 br1 = *(const uint4*)(Bp + 8);

    for (int k0 = 0; k0 < DMODEL; k0 += 32) {
        __syncthreads();
        *(uint4*)&As[arow][acol]     = ar;
        *(uint4*)&Bs[brow][bcol]     = br0;
        *(uint4*)&Bs[brow][bcol + 8] = br1;
        __syncthreads();
        if (k0 + 32 < DMODEL) {
            ar  = load_a(k0 + 32);
            br0 = *(const uint4*)(Bp + k0 + 32);
            br1 = *(const uint4*)(Bp + k0 + 40);
        }
        short8 af[2], bf[4];
#pragma unroll
        for (int i = 0; i < 2; ++i)
            af[i] = *(const short8*)&As[wm + i * 16 + l15][quad * 8];
#pragma unroll
        for (int j = 0; j < 4; ++j)
            bf[j] = *(const short8*)&Bs[wn + j * 16 + l15][quad * 8];
#pragma unroll
        for (int i = 0; i < 2; ++i)
#pragma unroll
            for (int j = 0; j < 4; ++j)
                acc[i][j] = __builtin_amdgcn_mfma_f32_16x16x32_bf16(af[i], bf[j], acc[i][j], 0, 0, 0);
    }

#pragma unroll
    for (int i = 0; i < 2; ++i)
#pragma unroll
        for (int j = 0; j < 4; ++j) {
            const int cl = nl0 + wn + j * 16 + l15;
#pragma unroll
            for (int r4 = 0; r4 < 4; ++r4) {
                const int r = m0 + wm + i * 16 + quad * 4 + r4;
                Dout[(size_t)r * 1024 + cl] = acc[i][j][r4];
            }
        }
}

// ---------------------------------------------------------------------------
// MFMA flash attention, key-split x2. Grid (32,16,2), 256 thr / 4 waves,
// 4 blocks/CU. No-max softmax; S^T-form QK^T so P packs as 4x ds_write_b64;
// scalar per-lane l. K: double-buffered LDS (1 barrier/iter); V: coalesced
// frag loads from FV in-iter. Partial O (fp32) + partial l per split.
// ---------------------------------------------------------------------------
__global__ __launch_bounds__(256, 3) void attn(
    const u16* __restrict__ Qb, const u16* __restrict__ Kb,
    const u16* __restrict__ FV, float* __restrict__ Opart, float* __restrict__ Lpart)
{
    __shared__ u16 Ks[2][64][72];   // [buf][key][d]
    __shared__ u16 Ps[4][16][68];   // [wave][q][key]

    const int t = threadIdx.x;
    const int n0 = blockIdx.x * 64;
    const int h = blockIdx.y, kvh = h >> 2;
    const int sp = blockIdx.z;
    const int w = t >> 6, lane = t & 63;
    const int quad = lane >> 4, l15 = lane & 15;
    const int srow = t >> 2, ssel = (t & 3) * 16;

    // Q frags (B-operand of S^T): B[k=d][n=q]
    const u16* qp = Qb + (size_t)(n0 + w * 16 + l15) * (NH * HDIM) + h * HDIM + quad * 8;
    const short8 aq0 = *(const short8*)qp;
    const short8 aq1 = *(const short8*)(qp + 32);

    const u16* kbase = Kb + (size_t)srow * (NKV * HDIM) + kvh * HDIM + ssel;
    const u16* fvb = FV + ((size_t)kvh * 32 * 4096) + (size_t)lane * 8;

    f32x4 o[4];
#pragma unroll
    for (int i = 0; i < 4; ++i) o[i] = {0.f, 0.f, 0.f, 0.f};
    float l_acc = 0.f;

    const int kts = sp * 16, kte = kts + 16;
    // prologue: first K tile -> buf 0 (kts is even, so cur starts at 0)
    *(uint4*)&Ks[0][srow][ssel]     = *(const uint4*)(kbase + (size_t)(kts * 64) * (NKV * HDIM));
    *(uint4*)&Ks[0][srow][ssel + 8] = *(const uint4*)(kbase + (size_t)(kts * 64) * (NKV * HDIM) + 8);
    __syncthreads();

    for (int kt = kts; kt < kte; ++kt) {
        const int cur = kt & 1, nxt = cur ^ 1;
        const int ktn = (kt + 1 < kte) ? kt + 1 : kts;   // wrap: dead store
        uint4 kr0 = *(const uint4*)(kbase + (size_t)(ktn * 64) * (NKV * HDIM));
        uint4 kr1 = *(const uint4*)(kbase + (size_t)(ktn * 64) * (NKV * HDIM) + 8);
        // V frags for this iter (used after softmax; in-iter latency hiding)
        short8 vf0[4], vf1[4];
#pragma unroll
        for (int dt = 0; dt < 4; ++dt) {
            vf0[dt] = *(const short8*)(fvb + (size_t)kt * 4096 + (dt * 2 + 0) * 512);
            vf1[dt] = *(const short8*)(fvb + (size_t)kt * 4096 + (dt * 2 + 1) * 512);
        }
        // ---- S^T = K Q^T : D[m=key][n=q] ----
        f32x4 s[4];
#pragma unroll
        for (int nt = 0; nt < 4; ++nt) {
            short8 kb0 = *(const short8*)&Ks[cur][nt * 16 + l15][quad * 8];
            short8 kb1 = *(const short8*)&Ks[cur][nt * 16 + l15][quad * 8 + 32];
            f32x4 z = {0.f, 0.f, 0.f, 0.f};
            z = __builtin_amdgcn_mfma_f32_16x16x32_bf16(kb0, aq0, z, 0, 0, 0);
            z = __builtin_amdgcn_mfma_f32_16x16x32_bf16(kb1, aq1, z, 0, 0, 0);
            s[nt] = z;   // reg r: key = nt*16 + quad*4 + r, q = l15
        }
        // ---- p = exp2(s); scalar row-sum; P -> Ps[q][key] via b64 writes ----
#pragma unroll
        for (int nt = 0; nt < 4; ++nt) {
            float p0 = __builtin_amdgcn_exp2f(s[nt][0]);
            float p1 = __builtin_amdgcn_exp2f(s[nt][1]);
            float p2 = __builtin_amdgcn_exp2f(s[nt][2]);
            float p3 = __builtin_amdgcn_exp2f(s[nt][3]);
            l_acc += (p0 + p1) + (p2 + p3);
            uint2 pk; pk.x = pack2t(p0, p1); pk.y = pack2t(p2, p3);
            *(uint2*)&Ps[w][l15][nt * 16 + quad * 4] = pk;
        }
        const short8 ap0 = *(const short8*)&Ps[w][l15][quad * 8];
        const short8 ap1 = *(const short8*)&Ps[w][l15][quad * 8 + 32];
        // ---- O += P V : D[m=q][n=d] ----
#pragma unroll
        for (int dt = 0; dt < 4; ++dt) {
            o[dt] = __builtin_amdgcn_mfma_f32_16x16x32_bf16(ap0, vf0[dt], o[dt], 0, 0, 0);
            o[dt] = __builtin_amdgcn_mfma_f32_16x16x32_bf16(ap1, vf1[dt], o[dt], 0, 0, 0);
        }
        // ---- stage next K tile; single barrier ----
        *(uint4*)&Ks[nxt][srow][ssel]     = kr0;
        *(uint4*)&Ks[nxt][srow][ssel + 8] = kr1;
        __syncthreads();
    }

    // ---- epilogue: partial l (reduce across quads) and partial O (fp32) ----
    l_acc += __shfl_xor(l_acc, 16, 64);
    l_acc += __shfl_xor(l_acc, 32, 64);
    if (quad == 0)
        Lpart[((size_t)sp * NH + h) * N_TOK + n0 + w * 16 + l15] = l_acc;
    float* ob = Opart + (size_t)sp * N_TOK * DMODEL;
#pragma unroll
    for (int dt = 0; dt < 4; ++dt)
#pragma unroll
        for (int r = 0; r < 4; ++r) {
            const int qrow = n0 + w * 16 + quad * 4 + r;
            const int col = h * HDIM + dt * 16 + l15;
            ob[(size_t)qrow * DMODEL + col] = o[dt][r];
        }
}

// ---------------------------------------------------------------------------
extern "C" void kernel_launch(void* const* d_in, const int* in_sizes, int n_in,
                              void* d_out, int out_size, void* d_ws, size_t ws_size,
                              hipStream_t stream) {
    const float* x  = (const float*)d_in[0];
    const float* fc = (const float*)d_in[1];
    const float* fs = (const float*)d_in[2];
    const float* Wq = (const float*)d_in[3];
    const float* Wk = (const float*)d_in[4];
    const float* Wv = (const float*)d_in[5];
    const float* Wo = (const float*)d_in[6];
    float* out = (float*)d_out;

    u16* ws  = (u16*)d_ws;
    u16* xb  = ws;                         // 2048*1024
    u16* Wqt = xb  + (size_t)2048 * 1024;  // 1024*1024
    u16* Wkt = Wqt + (size_t)1024 * 1024;  // 256*1024
    u16* Wvt = Wkt + (size_t)256 * 1024;   // 256*1024
    u16* Wot = Wvt + (size_t)256 * 1024;   // 1024*1024
    u16* qb  = Wot + (size_t)1024 * 1024;  // 2048*1024
    u16* kb  = qb  + (size_t)2048 * 1024;  // 2048*256
    u16* fv  = kb  + (size_t)2048 * 256;   // 256*2048 (fragment-packed V)
    float* Op = (float*)(fv + (size_t)256 * 2048);  // 2 * 2048*1024 f32
    float* Lp = Op + (size_t)2 * 2048 * 1024;       // 2 * 16*2048 f32

    prep<<<dim3(16, 16, 5), dim3(256), 0, stream>>>(Wq, Wk, Wv, Wo, x,
                                                    Wqt, Wkt, Wvt, Wot, xb);
    gemm_qkv<<<dim3(16, 12), dim3(256), 0, stream>>>(xb, Wqt, Wkt, Wvt,
                                                     qb, kb, fv, fc, fs);
    attn<<<dim3(32, 16, 2), dim3(256), 0, stream>>>(qb, kb, fv, Op, Lp);
    gemm_out<<<dim3(32, 8), dim3(256), 0, stream>>>(Op, Op + (size_t)2048 * 1024,
                                                    Lp, Lp + (size_t)16 * 2048,
                                                    Wot, out);
}

// Round 8
// 157.598 us; speedup vs baseline: 1.0869x; 1.0869x over previous
//
#include <hip/hip_runtime.h>

#define N_TOK 2048
#define DMODEL 1024
#define NH 16
#define NKV 4
#define HDIM 64
#define SCALE_LOG2E 0.1803368801111204f  // (1/8) * log2(e)

typedef __attribute__((ext_vector_type(8))) short short8;
typedef __attribute__((ext_vector_type(4))) float f32x4;
typedef unsigned short u16;
typedef unsigned int u32;

__device__ __forceinline__ u16 f2bf(float x) {
    u32 u = __float_as_uint(x);
    u += 0x7FFF + ((u >> 16) & 1);   // round-to-nearest-even
    return (u16)(u >> 16);
}
__device__ __forceinline__ u32 pack2(float a, float b) {
    return (u32)f2bf(a) | ((u32)f2bf(b) << 16);
}
// pack high halves (truncating bf16) of two floats: [bf(a) | bf(b)<<16]
__device__ __forceinline__ u32 pack2t(float a, float b) {
    return __builtin_amdgcn_perm(__float_as_uint(b), __float_as_uint(a), 0x07060302u);
}

// ---------------------------------------------------------------------------
// prep: z=0..3 transpose W (K x NC) -> Wt (NC x K) bf16; z=4 convert x -> bf16
// ---------------------------------------------------------------------------
__global__ __launch_bounds__(256) void prep(
    const float* __restrict__ Wq, const float* __restrict__ Wk,
    const float* __restrict__ Wv, const float* __restrict__ Wo,
    const float* __restrict__ x,
    u16* __restrict__ Wqt, u16* __restrict__ Wkt, u16* __restrict__ Wvt,
    u16* __restrict__ Wot, u16* __restrict__ xb)
{
    const int z = blockIdx.z;
    const int t = threadIdx.x;
    if (z == 4) {
        size_t base = ((size_t)(blockIdx.y * 16 + blockIdx.x)) * 8192;
#pragma unroll
        for (int i = 0; i < 8; ++i) {
            float4 v = *(const float4*)(x + base + i * 1024 + t * 4);
            uint2 p; p.x = pack2(v.x, v.y); p.y = pack2(v.z, v.w);
            *(uint2*)(xb + base + i * 1024 + t * 4) = p;
        }
        return;
    }
    const float* W; u16* Wt; int NC;
    if      (z == 0) { W = Wq; Wt = Wqt; NC = 1024; }
    else if (z == 1) { W = Wk; Wt = Wkt; NC = 256; }
    else if (z == 2) { W = Wv; Wt = Wvt; NC = 256; }
    else             { W = Wo; Wt = Wot; NC = 1024; }
    const int n0 = blockIdx.x * 64;
    if (n0 >= NC) return;
    const int k0 = blockIdx.y * 64;
    __shared__ float T[64][68];
    const int row = t >> 2, cs = (t & 3) * 16;
#pragma unroll
    for (int i = 0; i < 4; ++i)
        *(float4*)&T[row][cs + i * 4] =
            *(const float4*)(W + (size_t)(k0 + row) * NC + n0 + cs + i * 4);
    __syncthreads();
    const int nl = t >> 2, ks = (t & 3) * 16;
    u32 pk[8];
#pragma unroll
    for (int i = 0; i < 8; ++i)
        pk[i] = pack2(T[ks + 2 * i][nl], T[ks + 2 * i + 1][nl]);
    u16* dst = Wt + (size_t)(n0 + nl) * DMODEL + k0 + ks;
    uint4 w0; w0.x = pk[0]; w0.y = pk[1]; w0.z = pk[2]; w0.w = pk[3];
    uint4 w1; w1.x = pk[4]; w1.y = pk[5]; w1.z = pk[6]; w1.w = pk[7];
    *(uint4*)(dst) = w0;
    *(uint4*)(dst + 8) = w1;
}

// ---------------------------------------------------------------------------
// QKV GEMM: tile 128x128, BK=32, 4 waves of 64x64.
// grid (16,12): by<8 -> Q (rope, x SCALE_LOG2E); 8,9 -> K (rope);
// 10,11 -> V in fragment-packed layout FV:
//   FV[((((g*32+kt)*4+dt)*2+c)*64 + quad*16 + l15)*8 + j]
//     = V[token = kt*64 + c*32 + quad*8 + j][d = dt*16 + l15]  (per kv-head g)
// ---------------------------------------------------------------------------
__global__ __launch_bounds__(256, 2) void gemm_qkv(
    const u16* __restrict__ A,
    const u16* __restrict__ B0, const u16* __restrict__ B1, const u16* __restrict__ B2,
    u16* __restrict__ D0, u16* __restrict__ D1, u16* __restrict__ FVout,
    const float* __restrict__ fc, const float* __restrict__ fs)
{
    __shared__ u16 As[128][40];
    __shared__ u16 Bs[128][40];
    const int t = threadIdx.x;
    const int m0 = blockIdx.x * 128;
    const int by = blockIdx.y;

    const u16* Bt; int nl0, ep;           // ep: 1 rope bf16, 2 FV
    u16* dbf = nullptr; int dstride = 0; float epsc = 1.f;
    if (by < 8)       { Bt = B0; nl0 = by * 128;        dbf = D0; ep = 1; dstride = 1024;
                        epsc = SCALE_LOG2E; }
    else if (by < 10) { Bt = B1; nl0 = (by - 8) * 128;  dbf = D1; ep = 1; dstride = 256; }
    else              { Bt = B2; nl0 = (by - 10) * 128; ep = 2; }

    const int w = t >> 6, lane = t & 63;
    const int quad = lane >> 4, l15 = lane & 15;
    const int wm = (w >> 1) * 64, wn = (w & 1) * 64;
    const int srow = t >> 1, sk = (t & 1) * 16;

    const u16* Ap = A + (size_t)(m0 + srow) * DMODEL + sk;
    const u16* Bp = Bt + (size_t)(nl0 + srow) * DMODEL + sk;

    f32x4 acc[4][4];
#pragma unroll
    for (int i = 0; i < 4; ++i)
#pragma unroll
        for (int j = 0; j < 4; ++j) acc[i][j] = {0.f, 0.f, 0.f, 0.f};

    uint4 ar0 = *(const uint4*)(Ap);
    uint4 ar1 = *(const uint4*)(Ap + 8);
    uint4 br0 = *(const uint4*)(Bp);
    uint4 br1 = *(const uint4*)(Bp + 8);

    for (int k0 = 0; k0 < DMODEL; k0 += 32) {
        __syncthreads();
        *(uint4*)&As[srow][sk]     = ar0;
        *(uint4*)&As[srow][sk + 8] = ar1;
        *(uint4*)&Bs[srow][sk]     = br0;
        *(uint4*)&Bs[srow][sk + 8] = br1;
        __syncthreads();
        if (k0 + 32 < DMODEL) {
            ar0 = *(const uint4*)(Ap + k0 + 32);
            ar1 = *(const uint4*)(Ap + k0 + 40);
            br0 = *(const uint4*)(Bp + k0 + 32);
            br1 = *(const uint4*)(Bp + k0 + 40);
        }
        short8 af[4], bf[4];
#pragma unroll
        for (int i = 0; i < 4; ++i)
            af[i] = *(const short8*)&As[wm + i * 16 + l15][quad * 8];
#pragma unroll
        for (int j = 0; j < 4; ++j)
            bf[j] = *(const short8*)&Bs[wn + j * 16 + l15][quad * 8];
#pragma unroll
        for (int i = 0; i < 4; ++i)
#pragma unroll
            for (int j = 0; j < 4; ++j)
                acc[i][j] = __builtin_amdgcn_mfma_f32_16x16x32_bf16(af[i], bf[j], acc[i][j], 0, 0, 0);
    }

#pragma unroll
    for (int i = 0; i < 4; ++i)
#pragma unroll
        for (int j = 0; j < 4; ++j) {
            const int cl = nl0 + wn + j * 16 + l15;
#pragma unroll
            for (int r4 = 0; r4 < 4; ++r4) {
                const int r = m0 + wm + i * 16 + quad * 4 + r4;
                float own = acc[i][j][r4];
                if (ep == 1) {
                    float other = __shfl_xor(own, 1, 64);
                    const int p = (cl & 63) >> 1;
                    const float c = fc[r * 32 + p] * epsc, s = fs[r * 32 + p] * epsc;
                    float outv = ((cl & 1) == 0) ? (own * c - other * s)
                                                 : (other * s + own * c);
                    dbf[(size_t)r * dstride + cl] = f2bf(outv);
                } else {
                    const int g = cl >> 6, d = cl & 63;
                    const int dt = d >> 4, l15v = d & 15;
                    const int kt = r >> 6, klo = r & 63;
                    const int c = klo >> 5, k5 = klo & 31;
                    const int qd = k5 >> 3, jv = k5 & 7;
                    size_t idx = ((((size_t)(g * 32 + kt) * 4 + dt) * 2 + c) * 64
                                  + qd * 16 + l15v) * 8 + jv;
                    FVout[idx] = f2bf(own);
                }
            }
        }
}

// ---------------------------------------------------------------------------
// Output GEMM: tile 64x128, BK=32, 4 waves of 32x64, fp32 out. grid (32,8).
// ---------------------------------------------------------------------------
__global__ __launch_bounds__(256, 2) void gemm_out(
    const u16* __restrict__ A, const u16* __restrict__ Bt, float* __restrict__ Dout)
{
    __shared__ u16 As[64][40];
    __shared__ u16 Bs[128][40];
    const int t = threadIdx.x;
    const int m0 = blockIdx.x * 64;
    const int nl0 = blockIdx.y * 128;

    const int w = t >> 6, lane = t & 63;
    const int quad = lane >> 4, l15 = lane & 15;
    const int wm = (w >> 1) * 32, wn = (w & 1) * 64;
    const int arow = t >> 2, acol = (t & 3) * 8;
    const int brow = t >> 1, bcol = (t & 1) * 16;

    const u16* Ap = A + (size_t)(m0 + arow) * DMODEL + acol;
    const u16* Bp = Bt + (size_t)(nl0 + brow) * DMODEL + bcol;

    f32x4 acc[2][4];
#pragma unroll
    for (int i = 0; i < 2; ++i)
#pragma unroll
        for (int j = 0; j < 4; ++j) acc[i][j] = {0.f, 0.f, 0.f, 0.f};

    uint4 ar  = *(const uint4*)(Ap);
    uint4 br0 = *(const uint4*)(Bp);
    uint4 br1 = *(const uint4*)(Bp + 8);

    for (int k0 = 0; k0 < DMODEL; k0 += 32) {
        __syncthreads();
        *(uint4*)&As[arow][acol]     = ar;
        *(uint4*)&Bs[brow][bcol]     = br0;
        *(uint4*)&Bs[brow][bcol + 8] = br1;
        __syncthreads();
        if (k0 + 32 < DMODEL) {
            ar  = *(const uint4*)(Ap + k0 + 32);
            br0 = *(const uint4*)(Bp + k0 + 32);
            br1 = *(const uint4*)(Bp + k0 + 40);
        }
        short8 af[2], bf[4];
#pragma unroll
        for (int i = 0; i < 2; ++i)
            af[i] = *(const short8*)&As[wm + i * 16 + l15][quad * 8];
#pragma unroll
        for (int j = 0; j < 4; ++j)
            bf[j] = *(const short8*)&Bs[wn + j * 16 + l15][quad * 8];
#pragma unroll
        for (int i = 0; i < 2; ++i)
#pragma unroll
            for (int j = 0; j < 4; ++j)
                acc[i][j] = __builtin_amdgcn_mfma_f32_16x16x32_bf16(af[i], bf[j], acc[i][j], 0, 0, 0);
    }

#pragma unroll
    for (int i = 0; i < 2; ++i)
#pragma unroll
        for (int j = 0; j < 4; ++j) {
            const int cl = nl0 + wn + j * 16 + l15;
#pragma unroll
            for (int r4 = 0; r4 < 4; ++r4) {
                const int r = m0 + wm + i * 16 + quad * 4 + r4;
                Dout[(size_t)r * 1024 + cl] = acc[i][j][r4];
            }
        }
}

// ---------------------------------------------------------------------------
// MFMA flash attention. Grid (32,16), 256 thr / 4 waves, 2 blocks/CU.
// 128 keys per barrier round (16 rounds); each round = TWO independent
// S^T -> exp2 -> PV chains (subtiles of 64 keys) for ILP against latency.
// K: double-buffered LDS (stores just before barrier, loads at round start).
// V: frags loaded from FV in-iter AFTER the barrier (never drained by it).
// P: S^T C-layout -> 4x ds_write_b64 -> A-frag b128 reads (wave-private).
// No-max softmax (scale*log2e folded into Q); scalar per-lane l.
// ---------------------------------------------------------------------------
__global__ __launch_bounds__(256, 2) void attn(
    const u16* __restrict__ Qb, const u16* __restrict__ Kb,
    const u16* __restrict__ FV, u16* __restrict__ Ob)
{
    __shared__ u16 Ks[2][128][72];     // [buf][key][d]
    __shared__ u16 Ps[4][2][16][68];   // [wave][sub][q][key]

    const int t = threadIdx.x;
    const int n0 = blockIdx.x * 64;
    const int h = blockIdx.y, kvh = h >> 2;
    const int w = t >> 6, lane = t & 63;
    const int quad = lane >> 4, l15 = lane & 15;
    const int srow = t >> 1, ssel = (t & 1) * 32;   // staging: 128 rows x 64d, 32 elems/thread

    // Q frags (B-operand of S^T): B[k=d][n=q]
    const u16* qp = Qb + (size_t)(n0 + w * 16 + l15) * (NH * HDIM) + h * HDIM + quad * 8;
    const short8 aq0 = *(const short8*)qp;
    const short8 aq1 = *(const short8*)(qp + 32);

    const u16* kbase = Kb + (size_t)srow * (NKV * HDIM) + kvh * HDIM + ssel;
    const u16* fvb = FV + ((size_t)kvh * 32 * 4096) + (size_t)lane * 8;

    f32x4 o[4];
#pragma unroll
    for (int i = 0; i < 4; ++i) o[i] = {0.f, 0.f, 0.f, 0.f};
    float l_acc = 0.f;

    // prologue: keys 0..127 -> buf 0
#pragma unroll
    for (int c = 0; c < 4; ++c)
        *(uint4*)&Ks[0][srow][ssel + c * 8] = *(const uint4*)(kbase + c * 8);
    __syncthreads();

    for (int rd = 0; rd < 16; ++rd) {
        const int cur = rd & 1, nxt = cur ^ 1;
        const int rdn = (rd + 1) & 15;            // wrap: dead store on last round
        // prefetch next 128-key tile to regs (arrives during this round)
        uint4 kr[4];
#pragma unroll
        for (int c = 0; c < 4; ++c)
            kr[c] = *(const uint4*)(kbase + (size_t)(rdn * 128) * (NKV * HDIM) + c * 8);

#pragma unroll
        for (int sub = 0; sub < 2; ++sub) {
            const int kt = rd * 2 + sub;          // 64-key tile index (FV layout)
            // ---- V frags, in-iter (used ~after softmax) ----
            short8 vf0[4], vf1[4];
#pragma unroll
            for (int dt = 0; dt < 4; ++dt) {
                vf0[dt] = *(const short8*)(fvb + (size_t)kt * 4096 + (dt * 2 + 0) * 512);
                vf1[dt] = *(const short8*)(fvb + (size_t)kt * 4096 + (dt * 2 + 1) * 512);
            }
            // ---- S^T = K Q^T : D[m=key][n=q] ----
            f32x4 s[4];
#pragma unroll
            for (int nt = 0; nt < 4; ++nt) {
                short8 kb0 = *(const short8*)&Ks[cur][sub * 64 + nt * 16 + l15][quad * 8];
                short8 kb1 = *(const short8*)&Ks[cur][sub * 64 + nt * 16 + l15][quad * 8 + 32];
                f32x4 z = {0.f, 0.f, 0.f, 0.f};
                z = __builtin_amdgcn_mfma_f32_16x16x32_bf16(kb0, aq0, z, 0, 0, 0);
                z = __builtin_amdgcn_mfma_f32_16x16x32_bf16(kb1, aq1, z, 0, 0, 0);
                s[nt] = z;   // reg r: key = nt*16 + quad*4 + r, q = l15
            }
            // ---- p = exp2(s); scalar row-sum; P -> Ps via b64 writes ----
#pragma unroll
            for (int nt = 0; nt < 4; ++nt) {
                float p0 = __builtin_amdgcn_exp2f(s[nt][0]);
                float p1 = __builtin_amdgcn_exp2f(s[nt][1]);
                float p2 = __builtin_amdgcn_exp2f(s[nt][2]);
                float p3 = __builtin_amdgcn_exp2f(s[nt][3]);
                l_acc += (p0 + p1) + (p2 + p3);
                uint2 pk; pk.x = pack2t(p0, p1); pk.y = pack2t(p2, p3);
                *(uint2*)&Ps[w][sub][l15][nt * 16 + quad * 4] = pk;
            }
            const short8 ap0 = *(const short8*)&Ps[w][sub][l15][quad * 8];
            const short8 ap1 = *(const short8*)&Ps[w][sub][l15][quad * 8 + 32];
            // ---- O += P V : D[m=q][n=d] ----
#pragma unroll
            for (int dt = 0; dt < 4; ++dt) {
                o[dt] = __builtin_amdgcn_mfma_f32_16x16x32_bf16(ap0, vf0[dt], o[dt], 0, 0, 0);
                o[dt] = __builtin_amdgcn_mfma_f32_16x16x32_bf16(ap1, vf1[dt], o[dt], 0, 0, 0);
            }
        }
        // ---- stage next 128-key tile; single barrier (loads already arrived) ----
#pragma unroll
        for (int c = 0; c < 4; ++c)
            *(uint4*)&Ks[nxt][srow][ssel + c * 8] = kr[c];
        __syncthreads();
    }

    // ---- epilogue: reduce l across quads; every lane ends with l(q=l15) ----
    l_acc += __shfl_xor(l_acc, 16, 64);
    l_acc += __shfl_xor(l_acc, 32, 64);
    float linv[4];
#pragma unroll
    for (int r = 0; r < 4; ++r)
        linv[r] = 1.f / __shfl(l_acc, quad * 4 + r, 16);
#pragma unroll
    for (int dt = 0; dt < 4; ++dt)
#pragma unroll
        for (int r = 0; r < 4; ++r) {
            const int qrow = n0 + w * 16 + quad * 4 + r;
            const int col = h * HDIM + dt * 16 + l15;
            Ob[(size_t)qrow * (NH * HDIM) + col] = f2bf(o[dt][r] * linv[r]);
        }
}

// ---------------------------------------------------------------------------
extern "C" void kernel_launch(void* const* d_in, const int* in_sizes, int n_in,
                              void* d_out, int out_size, void* d_ws, size_t ws_size,
                              hipStream_t stream) {
    const float* x  = (const float*)d_in[0];
    const float* fc = (const float*)d_in[1];
    const float* fs = (const float*)d_in[2];
    const float* Wq = (const float*)d_in[3];
    const float* Wk = (const float*)d_in[4];
    const float* Wv = (const float*)d_in[5];
    const float* Wo = (const float*)d_in[6];
    float* out = (float*)d_out;

    u16* ws  = (u16*)d_ws;
    u16* xb  = ws;                         // 2048*1024
    u16* Wqt = xb  + (size_t)2048 * 1024;  // 1024*1024
    u16* Wkt = Wqt + (size_t)1024 * 1024;  // 256*1024
    u16* Wvt = Wkt + (size_t)256 * 1024;   // 256*1024
    u16* Wot = Wvt + (size_t)256 * 1024;   // 1024*1024
    u16* qb  = Wot + (size_t)1024 * 1024;  // 2048*1024
    u16* kb  = qb  + (size_t)2048 * 1024;  // 2048*256
    u16* fv  = kb  + (size_t)2048 * 256;   // 256*2048 (fragment-packed V)
    u16* aob = fv  + (size_t)256 * 2048;   // 2048*1024

    prep<<<dim3(16, 16, 5), dim3(256), 0, stream>>>(Wq, Wk, Wv, Wo, x,
                                                    Wqt, Wkt, Wvt, Wot, xb);
    gemm_qkv<<<dim3(16, 12), dim3(256), 0, stream>>>(xb, Wqt, Wkt, Wvt,
                                                     qb, kb, fv, fc, fs);
    attn<<<dim3(32, 16), dim3(256), 0, stream>>>(qb, kb, fv, aob);
    gemm_out<<<dim3(32, 8), dim3(256), 0, stream>>>(aob, Wot, out);
}